// Round 1
// baseline (5267.520 us; speedup 1.0000x reference)
//
#include <hip/hip_runtime.h>
#include <stdint.h>

#define T_HIST 60
#define T_OUT 360
#define H 128
#define L4H 512
#define KDIM 256          // fused K = H(x) + H(h)
#define R 16              // batch rows per block
#define NTHREADS 256
#define NBLOCKS 256       // 4096 / 16
#define ASTRIDE (KDIM + 8)
#define ZSTRIDE (H + 4)

typedef __attribute__((ext_vector_type(8))) __bf16 bf16x8;
typedef __attribute__((ext_vector_type(8))) unsigned short ushort8;
typedef __attribute__((ext_vector_type(4))) float f32x4;

static __device__ __forceinline__ unsigned short f2bf(float f) {
    union { float f; uint32_t u; } v; v.f = f;
    uint32_t r = v.u + 0x7fffu + ((v.u >> 16) & 1u);   // round-to-nearest-even
    return (unsigned short)(r >> 16);
}
static __device__ __forceinline__ float sigm(float x) { return 1.0f / (1.0f + __expf(-x)); }
static __device__ __forceinline__ float tanh_(float x) { return 2.0f / (1.0f + __expf(-2.0f * x)) - 1.0f; }

// Pack fused [Wih | Whh] (512 x 256) row-major bf16 for enc+dec, and b = bih+bhh.
__global__ void prep_kernel(
    const float* __restrict__ enc_Wih, const float* __restrict__ enc_Whh,
    const float* __restrict__ dec_Wih, const float* __restrict__ dec_Whh,
    const float* __restrict__ enc_bih, const float* __restrict__ enc_bhh,
    const float* __restrict__ dec_bih, const float* __restrict__ dec_bhh,
    unsigned short* __restrict__ Wenc, unsigned short* __restrict__ Wdec,
    float* __restrict__ benc, float* __restrict__ bdec)
{
    int idx = blockIdx.x * blockDim.x + threadIdx.x;
    const int total = 2 * L4H * KDIM;          // 262144
    if (idx < total) {
        int l = idx / (L4H * KDIM);
        int rem = idx - l * (L4H * KDIM);
        int n = rem / KDIM;
        int k = rem - n * KDIM;
        int src = (l * L4H + n) * H + (k < H ? k : k - H);
        float ve = (k < H) ? enc_Wih[src] : enc_Whh[src];
        float vd = (k < H) ? dec_Wih[src] : dec_Whh[src];
        Wenc[idx] = f2bf(ve);
        Wdec[idx] = f2bf(vd);
    }
    if (idx < 2 * L4H) {
        benc[idx] = enc_bih[idx] + enc_bhh[idx];
        bdec[idx] = dec_bih[idx] + dec_bhh[idx];
    }
}

// z = [x|h] @ W^T + b for one layer-step; wave w produces gate w's 128 columns.
// A (LDS): 16 x 256 bf16 row-major (padded).  W (global, L2-resident): 512 x 256 bf16 row-major.
// MFMA 16x16x32 bf16: A frag row=lane&15,k=quad*8+j ; B frag col(n)=lane&15,k=quad*8+j ;
// D: col=lane&15, row=quad*4+reg.
__device__ __forceinline__ void gemm_gates(const unsigned short* Abase,
                                           const unsigned short* __restrict__ W,
                                           const float* __restrict__ bias,
                                           float* zbase, int w, int lane)
{
    const int ln = lane & 15;
    const int quad = lane >> 4;
    f32x4 acc[8];
#pragma unroll
    for (int j = 0; j < 8; ++j) acc[j] = (f32x4){0.f, 0.f, 0.f, 0.f};
    const unsigned short* wbase = W + (size_t)(w * 128 + ln) * KDIM + quad * 8;
    const unsigned short* abase = Abase + ln * ASTRIDE + quad * 8;
#pragma unroll
    for (int q = 0; q < 8; ++q) {
        bf16x8 a = __builtin_bit_cast(bf16x8, *(const ushort8*)(abase + q * 32));
#pragma unroll
        for (int j = 0; j < 8; ++j) {
            bf16x8 b = __builtin_bit_cast(bf16x8, *(const ushort8*)(wbase + j * 16 * KDIM + q * 32));
            acc[j] = __builtin_amdgcn_mfma_f32_16x16x32_bf16(a, b, acc[j], 0, 0, 0);
        }
    }
#pragma unroll
    for (int j = 0; j < 8; ++j) {
        const int cc = j * 16 + ln;               // 0..127 within this gate
        const float bv = bias[w * 128 + cc];
#pragma unroll
        for (int i = 0; i < 4; ++i) {
            const int r = quad * 4 + i;
            zbase[(w * R + r) * ZSTRIDE + cc] = acc[j][i] + bv;
        }
    }
}

__global__ __launch_bounds__(NTHREADS, 1) void lstm_kernel(
    const float* __restrict__ hist,
    const float* __restrict__ emb_W, const float* __restrict__ emb_b,
    const unsigned short* __restrict__ Wenc, const float* __restrict__ benc,
    const unsigned short* __restrict__ Wdec, const float* __restrict__ bdec,
    const float* __restrict__ out_W, const float* __restrict__ out_b,
    float* __restrict__ out)
{
    __shared__ unsigned short A0[R][ASTRIDE];   // [x | h0]
    __shared__ unsigned short A1[R][ASTRIDE];   // [h0 | h1]
    __shared__ float zbuf[4][R][ZSTRIDE];       // gates i,f,g,o (fp32 pre-activations)
    __shared__ float c0[R][H], c1[R][H], h1f[R][H];
    __shared__ float predbuf[R][2];
    __shared__ float embW0[H], embW1[H], embB[H];
    __shared__ float outWs[2][H];
    __shared__ float outBs[2];
    __shared__ float histb[R][2];

    const int tid = threadIdx.x;
    const int lane = tid & 63;
    const int w = tid >> 6;
    const int row0 = blockIdx.x * R;

    if (tid < H) {
        embW0[tid] = emb_W[tid * 2 + 0];
        embW1[tid] = emb_W[tid * 2 + 1];
        embB[tid]  = emb_b[tid];
        outWs[0][tid] = out_W[tid];
        outWs[1][tid] = out_W[H + tid];
    }
    if (tid < 2) outBs[tid] = out_b[tid];
    for (int e = tid; e < R * H; e += NTHREADS) {
        int r = e >> 7, cc = e & 127;
        c0[r][cc] = 0.f; c1[r][cc] = 0.f;
        A0[r][H + cc] = 0; A1[r][cc] = 0; A1[r][H + cc] = 0;
    }
    __syncthreads();

    const unsigned short* We0 = Wenc;
    const unsigned short* We1 = Wenc + L4H * KDIM;
    const unsigned short* Wd0 = Wdec;
    const unsigned short* Wd1 = Wdec + L4H * KDIM;
    float* zb = &zbuf[0][0][0];

    // ---------------- encoder: 60 steps ----------------
#pragma unroll 1
    for (int t = 0; t < T_HIST; ++t) {
        if (tid < R * 2) {
            int r = tid >> 1, d = tid & 1;
            histb[r][d] = hist[(size_t)(row0 + r) * (T_HIST * 2) + t * 2 + d];
        }
        __syncthreads();
        for (int e = tid; e < R * H; e += NTHREADS) {
            int r = e >> 7, cc = e & 127;
            float x = histb[r][0] * embW0[cc] + histb[r][1] * embW1[cc] + embB[cc];
            A0[r][cc] = f2bf(x);
        }
        __syncthreads();
        gemm_gates(&A0[0][0], We0, benc, zb, w, lane);
        __syncthreads();
        for (int e = tid; e < R * H; e += NTHREADS) {   // layer0 elementwise
            int r = e >> 7, cc = e & 127;
            float iv = sigm(zbuf[0][r][cc]);
            float fv = sigm(zbuf[1][r][cc]);
            float gv = tanh_(zbuf[2][r][cc]);
            float ov = sigm(zbuf[3][r][cc]);
            float cn = fv * c0[r][cc] + iv * gv;
            float hn = ov * tanh_(cn);
            c0[r][cc] = cn;
            unsigned short hb = f2bf(hn);
            A0[r][H + cc] = hb;    // h0 for next step's layer0
            A1[r][cc] = hb;        // h0 as input to layer1
        }
        __syncthreads();
        gemm_gates(&A1[0][0], We1, benc + L4H, zb, w, lane);
        __syncthreads();
        for (int e = tid; e < R * H; e += NTHREADS) {   // layer1 elementwise
            int r = e >> 7, cc = e & 127;
            float iv = sigm(zbuf[0][r][cc]);
            float fv = sigm(zbuf[1][r][cc]);
            float gv = tanh_(zbuf[2][r][cc]);
            float ov = sigm(zbuf[3][r][cc]);
            float cn = fv * c1[r][cc] + iv * gv;
            float hn = ov * tanh_(cn);
            c1[r][cc] = cn;
            A1[r][H + cc] = f2bf(hn);
        }
        __syncthreads();
    }

    // ---------------- decoder: 360 autoregressive steps ----------------
#pragma unroll 1
    for (int t = 0; t < T_OUT; ++t) {
        for (int e = tid; e < R * H; e += NTHREADS) {   // re-embed previous pred (zeros at t=0)
            int r = e >> 7, cc = e & 127;
            float x = (t == 0) ? 0.f
                               : (predbuf[r][0] * embW0[cc] + predbuf[r][1] * embW1[cc] + embB[cc]);
            A0[r][cc] = f2bf(x);
        }
        __syncthreads();
        gemm_gates(&A0[0][0], Wd0, bdec, zb, w, lane);
        __syncthreads();
        for (int e = tid; e < R * H; e += NTHREADS) {   // layer0 elementwise
            int r = e >> 7, cc = e & 127;
            float iv = sigm(zbuf[0][r][cc]);
            float fv = sigm(zbuf[1][r][cc]);
            float gv = tanh_(zbuf[2][r][cc]);
            float ov = sigm(zbuf[3][r][cc]);
            float cn = fv * c0[r][cc] + iv * gv;
            float hn = ov * tanh_(cn);
            c0[r][cc] = cn;
            unsigned short hb = f2bf(hn);
            A0[r][H + cc] = hb;
            A1[r][cc] = hb;
        }
        __syncthreads();
        gemm_gates(&A1[0][0], Wd1, bdec + L4H, zb, w, lane);
        __syncthreads();
        for (int e = tid; e < R * H; e += NTHREADS) {   // layer1 elementwise
            int r = e >> 7, cc = e & 127;
            float iv = sigm(zbuf[0][r][cc]);
            float fv = sigm(zbuf[1][r][cc]);
            float gv = tanh_(zbuf[2][r][cc]);
            float ov = sigm(zbuf[3][r][cc]);
            float cn = fv * c1[r][cc] + iv * gv;
            float hn = ov * tanh_(cn);
            c1[r][cc] = cn;
            A1[r][H + cc] = f2bf(hn);
            h1f[r][cc] = hn;       // fp32 copy for output projection
        }
        __syncthreads();
        {   // pred = h1 @ out_W^T + out_b ; write output; stash for re-embed
            int r = tid >> 4, d = (tid >> 3) & 1, part = tid & 7;
            float p = 0.f;
#pragma unroll
            for (int jj = 0; jj < 16; ++jj) {
                int cc = part * 16 + jj;
                p += h1f[r][cc] * outWs[d][cc];
            }
            p += __shfl_down(p, 4);
            p += __shfl_down(p, 2);
            p += __shfl_down(p, 1);
            if (part == 0) {
                p += outBs[d];
                predbuf[r][d] = p;
                out[(size_t)(row0 + r) * (T_OUT * 2) + t * 2 + d] = p;
            }
        }
        __syncthreads();
    }
}

extern "C" void kernel_launch(void* const* d_in, const int* in_sizes, int n_in,
                              void* d_out, int out_size, void* d_ws, size_t ws_size,
                              hipStream_t stream) {
    const float* hist    = (const float*)d_in[0];
    const float* emb_W   = (const float*)d_in[1];
    const float* emb_b   = (const float*)d_in[2];
    const float* enc_Wih = (const float*)d_in[3];
    const float* enc_Whh = (const float*)d_in[4];
    const float* enc_bih = (const float*)d_in[5];
    const float* enc_bhh = (const float*)d_in[6];
    const float* dec_Wih = (const float*)d_in[7];
    const float* dec_Whh = (const float*)d_in[8];
    const float* dec_bih = (const float*)d_in[9];
    const float* dec_bhh = (const float*)d_in[10];
    const float* out_W   = (const float*)d_in[11];
    const float* out_b   = (const float*)d_in[12];

    char* ws = (char*)d_ws;
    unsigned short* Wenc = (unsigned short*)ws;                       // 2*512*256 bf16 = 512 KB
    unsigned short* Wdec = (unsigned short*)(ws + 524288);            // 512 KB
    float* benc = (float*)(ws + 1048576);                             // 2*512 f32
    float* bdec = (float*)(ws + 1048576 + 4096);

    prep_kernel<<<1024, 256, 0, stream>>>(enc_Wih, enc_Whh, dec_Wih, dec_Whh,
                                          enc_bih, enc_bhh, dec_bih, dec_bhh,
                                          Wenc, Wdec, benc, bdec);
    lstm_kernel<<<NBLOCKS, NTHREADS, 0, stream>>>(hist, emb_W, emb_b,
                                                  Wenc, benc, Wdec, bdec,
                                                  out_W, out_b, (float*)d_out);
}

// Round 2
// 3747.200 us; speedup vs baseline: 1.4057x; 1.4057x over previous
//
#include <hip/hip_runtime.h>
#include <stdint.h>

#define NT 512
#define PRS 722

typedef __attribute__((ext_vector_type(8))) __bf16 bf16x8;
typedef __attribute__((ext_vector_type(8))) unsigned short ushort8;
typedef __attribute__((ext_vector_type(4))) float f32x4;

static __device__ __forceinline__ unsigned short f2bf(float f) {
    union { float f; uint32_t u; } v; v.f = f;
    uint32_t r = v.u + 0x7fffu + ((v.u >> 16) & 1u);   // RNE
    return (unsigned short)(r >> 16);
}
static __device__ __forceinline__ float sigm(float x) { return 1.0f / (1.0f + __expf(-x)); }
static __device__ __forceinline__ float tanh_(float x) { return 2.0f / (1.0f + __expf(-2.0f * x)) - 1.0f; }
static __device__ __forceinline__ bf16x8 ld8(const unsigned short* p) {
    return __builtin_bit_cast(bf16x8, *(const ushort8*)p);
}
// XOR-swizzled LDS layouts (16B granules) -> conflict-free wave b128 reads
static __device__ __forceinline__ int a0i(int r, int k) {   // A0: [16][128]
    return r * 128 + ((((k >> 3) ^ (r & 7)) << 3)) + (k & 7);
}
static __device__ __forceinline__ int a1i(int r, int k) {   // A1: [16][256]
    return r * 256 + ((((k >> 3) ^ (r & 7)) << 3)) + (k & 7);
}

// ---- prep: pack weights bf16, fold embedding into M (512x2) and v (512), sum biases ----
__global__ void prep_kernel(
    const float* __restrict__ emb_W, const float* __restrict__ emb_b,
    const float* __restrict__ enc_Wih, const float* __restrict__ enc_Whh,
    const float* __restrict__ dec_Wih, const float* __restrict__ dec_Whh,
    const float* __restrict__ enc_bih, const float* __restrict__ enc_bhh,
    const float* __restrict__ dec_bih, const float* __restrict__ dec_bhh,
    unsigned short* __restrict__ W0e, unsigned short* __restrict__ W1e,
    unsigned short* __restrict__ W0d, unsigned short* __restrict__ W1d,
    float* __restrict__ benc, float* __restrict__ bdec,
    float* __restrict__ Me, float* __restrict__ Md,
    float* __restrict__ ve, float* __restrict__ vd)
{
    int idx = blockIdx.x * blockDim.x + threadIdx.x;
    // layer1 fused [Wih | Whh]: 2 nets x 512 x 256
    if (idx < 2 * 512 * 256) {
        int net = idx >> 17;
        int rem = idx & 131071;
        int n = rem >> 8, k = rem & 255;
        const float* Wih = net ? dec_Wih : enc_Wih;
        const float* Whh = net ? dec_Whh : enc_Whh;
        float v = (k < 128) ? Wih[(size_t)(512 + n) * 128 + k]
                            : Whh[(size_t)(512 + n) * 128 + k - 128];
        (net ? W1d : W1e)[rem] = f2bf(v);
    }
    // layer0 h-part only (Whh): 2 nets x 512 x 128
    if (idx < 2 * 512 * 128) {
        int net = idx >> 16;
        int rem = idx & 65535;
        const float* Whh = net ? dec_Whh : enc_Whh;
        (net ? W0d : W0e)[rem] = f2bf(Whh[rem]);
    }
    // biases: 2 nets x (2 layers * 512)
    if (idx < 2048) {
        int net = idx >> 10;
        int rem = idx & 1023;
        float v = net ? (dec_bih[rem] + dec_bhh[rem]) : (enc_bih[rem] + enc_bhh[rem]);
        (net ? bdec : benc)[rem] = v;
    }
    // M = Wih_l0 @ emb_W (512x2), v = Wih_l0 @ emb_b (512), fp32 exact
    if (idx < 1024) {
        int net = idx >> 9, n = idx & 511;
        const float* Wih = net ? dec_Wih : enc_Wih;
        float m0 = 0.f, m1 = 0.f, vv = 0.f;
        for (int k = 0; k < 128; ++k) {
            float wv = Wih[(size_t)n * 128 + k];
            m0 += wv * emb_W[k * 2 + 0];
            m1 += wv * emb_W[k * 2 + 1];
            vv += wv * emb_b[k];
        }
        float* M = net ? Md : Me;
        float* V = net ? vd : ve;
        M[n * 2 + 0] = m0; M[n * 2 + 1] = m1; V[n] = vv;
    }
}

__global__ __launch_bounds__(NT, 2) void lstm_kernel(
    const float* __restrict__ hist,
    const unsigned short* __restrict__ W0e, const unsigned short* __restrict__ W1e,
    const unsigned short* __restrict__ W0d, const unsigned short* __restrict__ W1d,
    const float* __restrict__ benc, const float* __restrict__ bdec,
    const float* __restrict__ Me, const float* __restrict__ Md,
    const float* __restrict__ ve, const float* __restrict__ vd,
    const float* __restrict__ out_W, const float* __restrict__ out_b,
    float* __restrict__ out)
{
    __shared__ unsigned short A0[2][16 * 128];   // h0 ping-pong (swizzled)
    __shared__ unsigned short A1[2][16 * 256];   // [h0 | h1] ping-pong (swizzled)
    __shared__ float histL[16][120];
    __shared__ float predsL[16][PRS];
    __shared__ float ppart[8][16][2];
    __shared__ float predb[16][2];
    __shared__ float outbS[2];

    const int tid = threadIdx.x;
    const int w = tid >> 6;
    const int lane = tid & 63;
    const int ln = lane & 15;
    const int quad = lane >> 4;
    const int row0 = blockIdx.x * 16;
    const int cc0 = w * 16 + ln;          // col within H owned by this lane

    for (int e = tid; e < 16 * 128; e += NT) A0[0][e] = 0;
    for (int e = tid; e < 16 * 256; e += NT) A1[0][e] = 0;
    for (int e = tid; e < 16 * 120; e += NT) {
        int r = e / 120, j = e - r * 120;
        histL[r][j] = hist[(size_t)(row0 + r) * 120 + j];
    }
    if (tid < 2) outbS[tid] = out_b[tid];

    const float outWl0 = out_W[cc0];
    const float outWl1 = out_W[128 + cc0];

    bf16x8 wp0[4][4];                     // persistent layer0 (h-part) weights
    float b0c[4], b1c[4], M0c[4], M1c[4], vc[4];
    float c0r[4] = {0.f, 0.f, 0.f, 0.f};
    float c1r[4] = {0.f, 0.f, 0.f, 0.f};

    auto load_consts = [&](const unsigned short* W0, const float* bb,
                           const float* M, const float* V) {
#pragma unroll
        for (int g = 0; g < 4; ++g) {
            const int n = g * 128 + cc0;
#pragma unroll
            for (int q = 0; q < 4; ++q)
                wp0[g][q] = ld8(W0 + (size_t)n * 128 + quad * 8 + q * 32);
            b0c[g] = bb[n];
            b1c[g] = bb[512 + n];
            M0c[g] = M[n * 2 + 0];
            M1c[g] = M[n * 2 + 1];
            vc[g]  = V[n];
        }
    };

    load_consts(W0e, benc, Me, ve);
    __syncthreads();

    int cur = 0;

    // ================= encoder: 60 steps, 2 barriers/step =================
#pragma unroll 1
    for (int t = 0; t < 60; ++t) {
        const int nxt = cur ^ 1;
        // issue layer1 gate0/1 weight loads early (consumed after the barrier)
        bf16x8 wl0[8], wl1[8];
#pragma unroll
        for (int q = 0; q < 8; ++q) {
            wl0[q] = ld8(W1e + (size_t)(0 * 128 + cc0) * 256 + quad * 8 + q * 32);
            wl1[q] = ld8(W1e + (size_t)(1 * 128 + cc0) * 256 + quad * 8 + q * 32);
        }
        float p0[4], p1[4];
#pragma unroll
        for (int i = 0; i < 4; ++i) {
            p0[i] = histL[quad * 4 + i][2 * t];
            p1[i] = histL[quad * 4 + i][2 * t + 1];
        }
        f32x4 acc[4];
#pragma unroll
        for (int g = 0; g < 4; ++g)
#pragma unroll
            for (int i = 0; i < 4; ++i)
                acc[g][i] = b0c[g] + vc[g] + M0c[g] * p0[i] + M1c[g] * p1[i];
        bf16x8 a0[4];
#pragma unroll
        for (int q = 0; q < 4; ++q)
            a0[q] = ld8(&A0[cur][a0i(ln, quad * 8 + q * 32)]);
#pragma unroll
        for (int q = 0; q < 4; ++q)
#pragma unroll
            for (int g = 0; g < 4; ++g)
                acc[g] = __builtin_amdgcn_mfma_f32_16x16x32_bf16(a0[q], wp0[g][q], acc[g], 0, 0, 0);
        bf16x8 wl2[8];
#pragma unroll
        for (int q = 0; q < 8; ++q)
            wl2[q] = ld8(W1e + (size_t)(2 * 128 + cc0) * 256 + quad * 8 + q * 32);
        // elementwise layer0 (in-register)
#pragma unroll
        for (int i = 0; i < 4; ++i) {
            float iv = sigm(acc[0][i]);
            float fv = sigm(acc[1][i]);
            float gv = tanh_(acc[2][i]);
            float ov = sigm(acc[3][i]);
            c0r[i] = fv * c0r[i] + iv * gv;
            float h = ov * tanh_(c0r[i]);
            unsigned short hb = f2bf(h);
            int r = quad * 4 + i;
            A0[nxt][a0i(r, cc0)] = hb;
            A1[cur][a1i(r, cc0)] = hb;
        }
        __syncthreads();
        // ---- layer 1 ----
        bf16x8 a1[8];
#pragma unroll
        for (int q = 0; q < 8; ++q)
            a1[q] = ld8(&A1[cur][a1i(ln, quad * 8 + q * 32)]);
        f32x4 acc1[4];
#pragma unroll
        for (int g = 0; g < 4; ++g)
#pragma unroll
            for (int i = 0; i < 4; ++i) acc1[g][i] = b1c[g];
#pragma unroll
        for (int q = 0; q < 8; ++q)
            acc1[0] = __builtin_amdgcn_mfma_f32_16x16x32_bf16(a1[q], wl0[q], acc1[0], 0, 0, 0);
#pragma unroll
        for (int q = 0; q < 8; ++q)
            acc1[1] = __builtin_amdgcn_mfma_f32_16x16x32_bf16(a1[q], wl1[q], acc1[1], 0, 0, 0);
        bf16x8 wl3[8];
#pragma unroll
        for (int q = 0; q < 8; ++q)
            wl3[q] = ld8(W1e + (size_t)(3 * 128 + cc0) * 256 + quad * 8 + q * 32);
#pragma unroll
        for (int q = 0; q < 8; ++q)
            acc1[2] = __builtin_amdgcn_mfma_f32_16x16x32_bf16(a1[q], wl2[q], acc1[2], 0, 0, 0);
#pragma unroll
        for (int q = 0; q < 8; ++q)
            acc1[3] = __builtin_amdgcn_mfma_f32_16x16x32_bf16(a1[q], wl3[q], acc1[3], 0, 0, 0);
#pragma unroll
        for (int i = 0; i < 4; ++i) {
            float iv = sigm(acc1[0][i]);
            float fv = sigm(acc1[1][i]);
            float gv = tanh_(acc1[2][i]);
            float ov = sigm(acc1[3][i]);
            c1r[i] = fv * c1r[i] + iv * gv;
            float h = ov * tanh_(c1r[i]);
            A1[nxt][a1i(quad * 4 + i, 128 + cc0)] = f2bf(h);
        }
        __syncthreads();
        cur = nxt;
    }

    // reload persistent weights/consts for decoder
    load_consts(W0d, bdec, Md, vd);

    // ================= decoder: 360 steps, 3 barriers/step =================
#pragma unroll 1
    for (int t = 0; t < 360; ++t) {
        const int nxt = cur ^ 1;
        bf16x8 wl0[8], wl1[8];
#pragma unroll
        for (int q = 0; q < 8; ++q) {
            wl0[q] = ld8(W1d + (size_t)(0 * 128 + cc0) * 256 + quad * 8 + q * 32);
            wl1[q] = ld8(W1d + (size_t)(1 * 128 + cc0) * 256 + quad * 8 + q * 32);
        }
        f32x4 acc[4];
        if (t) {
            float p0[4], p1[4];
#pragma unroll
            for (int i = 0; i < 4; ++i) {
                p0[i] = predb[quad * 4 + i][0];
                p1[i] = predb[quad * 4 + i][1];
            }
#pragma unroll
            for (int g = 0; g < 4; ++g)
#pragma unroll
                for (int i = 0; i < 4; ++i)
                    acc[g][i] = b0c[g] + vc[g] + M0c[g] * p0[i] + M1c[g] * p1[i];
        } else {
#pragma unroll
            for (int g = 0; g < 4; ++g)
#pragma unroll
                for (int i = 0; i < 4; ++i) acc[g][i] = b0c[g];   // x = 0 at t=0
        }
        bf16x8 a0[4];
#pragma unroll
        for (int q = 0; q < 4; ++q)
            a0[q] = ld8(&A0[cur][a0i(ln, quad * 8 + q * 32)]);
#pragma unroll
        for (int q = 0; q < 4; ++q)
#pragma unroll
            for (int g = 0; g < 4; ++g)
                acc[g] = __builtin_amdgcn_mfma_f32_16x16x32_bf16(a0[q], wp0[g][q], acc[g], 0, 0, 0);
        bf16x8 wl2[8];
#pragma unroll
        for (int q = 0; q < 8; ++q)
            wl2[q] = ld8(W1d + (size_t)(2 * 128 + cc0) * 256 + quad * 8 + q * 32);
#pragma unroll
        for (int i = 0; i < 4; ++i) {
            float iv = sigm(acc[0][i]);
            float fv = sigm(acc[1][i]);
            float gv = tanh_(acc[2][i]);
            float ov = sigm(acc[3][i]);
            c0r[i] = fv * c0r[i] + iv * gv;
            float h = ov * tanh_(c0r[i]);
            unsigned short hb = f2bf(h);
            int r = quad * 4 + i;
            A0[nxt][a0i(r, cc0)] = hb;
            A1[cur][a1i(r, cc0)] = hb;
        }
        __syncthreads();
        bf16x8 a1[8];
#pragma unroll
        for (int q = 0; q < 8; ++q)
            a1[q] = ld8(&A1[cur][a1i(ln, quad * 8 + q * 32)]);
        f32x4 acc1[4];
#pragma unroll
        for (int g = 0; g < 4; ++g)
#pragma unroll
            for (int i = 0; i < 4; ++i) acc1[g][i] = b1c[g];
#pragma unroll
        for (int q = 0; q < 8; ++q)
            acc1[0] = __builtin_amdgcn_mfma_f32_16x16x32_bf16(a1[q], wl0[q], acc1[0], 0, 0, 0);
#pragma unroll
        for (int q = 0; q < 8; ++q)
            acc1[1] = __builtin_amdgcn_mfma_f32_16x16x32_bf16(a1[q], wl1[q], acc1[1], 0, 0, 0);
        bf16x8 wl3[8];
#pragma unroll
        for (int q = 0; q < 8; ++q)
            wl3[q] = ld8(W1d + (size_t)(3 * 128 + cc0) * 256 + quad * 8 + q * 32);
#pragma unroll
        for (int q = 0; q < 8; ++q)
            acc1[2] = __builtin_amdgcn_mfma_f32_16x16x32_bf16(a1[q], wl2[q], acc1[2], 0, 0, 0);
#pragma unroll
        for (int q = 0; q < 8; ++q)
            acc1[3] = __builtin_amdgcn_mfma_f32_16x16x32_bf16(a1[q], wl3[q], acc1[3], 0, 0, 0);
        float pp[8];
#pragma unroll
        for (int i = 0; i < 4; ++i) {
            float iv = sigm(acc1[0][i]);
            float fv = sigm(acc1[1][i]);
            float gv = tanh_(acc1[2][i]);
            float ov = sigm(acc1[3][i]);
            c1r[i] = fv * c1r[i] + iv * gv;
            float h = ov * tanh_(c1r[i]);
            A1[nxt][a1i(quad * 4 + i, 128 + cc0)] = f2bf(h);
            pp[i * 2 + 0] = h * outWl0;
            pp[i * 2 + 1] = h * outWl1;
        }
        // reduce projection partials over this wave's 16 columns
#pragma unroll
        for (int m = 1; m <= 8; m <<= 1)
#pragma unroll
            for (int k = 0; k < 8; ++k) pp[k] += __shfl_xor(pp[k], m);
        if (ln == 0) {
#pragma unroll
            for (int i = 0; i < 4; ++i) {
                ppart[w][quad * 4 + i][0] = pp[i * 2 + 0];
                ppart[w][quad * 4 + i][1] = pp[i * 2 + 1];
            }
        }
        __syncthreads();
        if (tid < 32) {
            int r = tid >> 1, d = tid & 1;
            float s = outbS[d];
#pragma unroll
            for (int ww = 0; ww < 8; ++ww) s += ppart[ww][r][d];
            predb[r][d] = s;
            predsL[r][2 * t + d] = s;
        }
        __syncthreads();
        cur = nxt;
    }

    // flush predictions (coalesced)
    for (int e = tid; e < 16 * 720; e += NT) {
        int r = e / 720, j = e - r * 720;
        out[(size_t)(row0 + r) * 720 + j] = predsL[r][j];
    }
}

extern "C" void kernel_launch(void* const* d_in, const int* in_sizes, int n_in,
                              void* d_out, int out_size, void* d_ws, size_t ws_size,
                              hipStream_t stream) {
    const float* hist    = (const float*)d_in[0];
    const float* emb_W   = (const float*)d_in[1];
    const float* emb_b   = (const float*)d_in[2];
    const float* enc_Wih = (const float*)d_in[3];
    const float* enc_Whh = (const float*)d_in[4];
    const float* enc_bih = (const float*)d_in[5];
    const float* enc_bhh = (const float*)d_in[6];
    const float* dec_Wih = (const float*)d_in[7];
    const float* dec_Whh = (const float*)d_in[8];
    const float* dec_bih = (const float*)d_in[9];
    const float* dec_bhh = (const float*)d_in[10];
    const float* out_W   = (const float*)d_in[11];
    const float* out_b   = (const float*)d_in[12];

    char* ws = (char*)d_ws;
    unsigned short* W0e = (unsigned short*)(ws + 0);        // 512*128*2 = 131072
    unsigned short* W1e = (unsigned short*)(ws + 131072);   // 512*256*2 = 262144
    unsigned short* W0d = (unsigned short*)(ws + 393216);   // 131072
    unsigned short* W1d = (unsigned short*)(ws + 524288);   // 262144
    float* benc = (float*)(ws + 786432);                    // 4096
    float* bdec = (float*)(ws + 790528);                    // 4096
    float* Me   = (float*)(ws + 794624);                    // 4096
    float* Md   = (float*)(ws + 798720);                    // 4096
    float* ve   = (float*)(ws + 802816);                    // 2048
    float* vd   = (float*)(ws + 804864);                    // 2048

    prep_kernel<<<1024, 256, 0, stream>>>(emb_W, emb_b,
                                          enc_Wih, enc_Whh, dec_Wih, dec_Whh,
                                          enc_bih, enc_bhh, dec_bih, dec_bhh,
                                          W0e, W1e, W0d, W1d,
                                          benc, bdec, Me, Md, ve, vd);
    lstm_kernel<<<256, NT, 0, stream>>>(hist, W0e, W1e, W0d, W1d,
                                        benc, bdec, Me, Md, ve, vd,
                                        out_W, out_b, (float*)d_out);
}

// Round 3
// 2125.392 us; speedup vs baseline: 2.4784x; 1.7631x over previous
//
#include <hip/hip_runtime.h>
#include <stdint.h>

#define NT 512

typedef __attribute__((ext_vector_type(8))) __bf16 bf16x8;
typedef __attribute__((ext_vector_type(8))) unsigned short ushort8;
typedef __attribute__((ext_vector_type(4))) float f32x4;

static __device__ __forceinline__ unsigned short f2bf(float f) {
    union { float f; uint32_t u; } v; v.f = f;
    uint32_t r = v.u + 0x7fffu + ((v.u >> 16) & 1u);   // RNE
    return (unsigned short)(r >> 16);
}
static __device__ __forceinline__ float sigm(float x) { return 1.0f / (1.0f + __expf(-x)); }
static __device__ __forceinline__ float tanh_(float x) { return 2.0f / (1.0f + __expf(-2.0f * x)) - 1.0f; }
static __device__ __forceinline__ bf16x8 ld8(const unsigned short* p) {
    return __builtin_bit_cast(bf16x8, *(const ushort8*)p);
}
// XOR-swizzled LDS layouts (16B granules keyed by row) -> balanced wave b128 reads
static __device__ __forceinline__ int a1i(int r, int k) {   // A1: [16][256]
    return r * 256 + (((k >> 3) ^ (r & 7)) << 3) + (k & 7);
}
static __device__ __forceinline__ int w0i(int n, int k) {   // W0s: [512][128]
    return n * 128 + (((k >> 3) ^ (n & 7)) << 3) + (k & 7);
}

// ---- prep: pack weights bf16, fold embedding into M (512x2) and v (512), sum biases ----
__global__ void prep_kernel(
    const float* __restrict__ emb_W, const float* __restrict__ emb_b,
    const float* __restrict__ enc_Wih, const float* __restrict__ enc_Whh,
    const float* __restrict__ dec_Wih, const float* __restrict__ dec_Whh,
    const float* __restrict__ enc_bih, const float* __restrict__ enc_bhh,
    const float* __restrict__ dec_bih, const float* __restrict__ dec_bhh,
    unsigned short* __restrict__ W0e, unsigned short* __restrict__ W1e,
    unsigned short* __restrict__ W0d, unsigned short* __restrict__ W1d,
    float* __restrict__ benc, float* __restrict__ bdec,
    float* __restrict__ Me, float* __restrict__ Md,
    float* __restrict__ ve, float* __restrict__ vd)
{
    int idx = blockIdx.x * blockDim.x + threadIdx.x;
    // layer1 fused [Wih | Whh]: 2 nets x 512 x 256
    if (idx < 2 * 512 * 256) {
        int net = idx >> 17;
        int rem = idx & 131071;
        int n = rem >> 8, k = rem & 255;
        const float* Wih = net ? dec_Wih : enc_Wih;
        const float* Whh = net ? dec_Whh : enc_Whh;
        float v = (k < 128) ? Wih[(size_t)(512 + n) * 128 + k]
                            : Whh[(size_t)(512 + n) * 128 + k - 128];
        (net ? W1d : W1e)[rem] = f2bf(v);
    }
    // layer0 h-part only (Whh): 2 nets x 512 x 128
    if (idx < 2 * 512 * 128) {
        int net = idx >> 16;
        int rem = idx & 65535;
        const float* Whh = net ? dec_Whh : enc_Whh;
        (net ? W0d : W0e)[rem] = f2bf(Whh[rem]);
    }
    // biases: 2 nets x (2 layers * 512)
    if (idx < 2048) {
        int net = idx >> 10;
        int rem = idx & 1023;
        float v = net ? (dec_bih[rem] + dec_bhh[rem]) : (enc_bih[rem] + enc_bhh[rem]);
        (net ? bdec : benc)[rem] = v;
    }
    // M = Wih_l0 @ emb_W (512x2), v = Wih_l0 @ emb_b (512), fp32 exact
    if (idx < 1024) {
        int net = idx >> 9, n = idx & 511;
        const float* Wih = net ? dec_Wih : enc_Wih;
        float m0 = 0.f, m1 = 0.f, vv = 0.f;
        for (int k = 0; k < 128; ++k) {
            float wv = Wih[(size_t)n * 128 + k];
            m0 += wv * emb_W[k * 2 + 0];
            m1 += wv * emb_W[k * 2 + 1];
            vv += wv * emb_b[k];
        }
        float* M = net ? Md : Me;
        float* V = net ? vd : ve;
        M[n * 2 + 0] = m0; M[n * 2 + 1] = m1; V[n] = vv;
    }
}

__global__ __launch_bounds__(NT, 2) void lstm_kernel(
    const float* __restrict__ hist,
    const unsigned short* __restrict__ W0e, const unsigned short* __restrict__ W1e,
    const unsigned short* __restrict__ W0d, const unsigned short* __restrict__ W1d,
    const float* __restrict__ benc, const float* __restrict__ bdec,
    const float* __restrict__ Me, const float* __restrict__ Md,
    const float* __restrict__ ve, const float* __restrict__ vd,
    const float* __restrict__ out_W, const float* __restrict__ out_b,
    float* __restrict__ out)
{
    __shared__ __align__(16) unsigned short A1[2][16 * 256];  // ping-pong [h0 | h1]
    __shared__ __align__(16) unsigned short W0s[512 * 128];   // layer0 Whh, LDS-resident
    __shared__ __align__(16) float histL[16 * 120];
    __shared__ float predb[2][16][2];                         // ping-pong pred (incl. out_b)
    __shared__ float outbS[2];

    const int tid = threadIdx.x;
    const int lane = tid & 63;
    const int w = tid >> 6;
    const int ln = lane & 15;
    const int quad = lane >> 4;
    const int row0 = blockIdx.x * 16;
    const int cc0 = w * 16 + ln;          // col within H owned by this lane

    for (int e = tid; e < 1024; e += NT) ((uint4*)A1)[e] = make_uint4(0u, 0u, 0u, 0u);
    for (int e = tid; e < 480; e += NT)
        ((float4*)histL)[e] = ((const float4*)(hist + (size_t)row0 * 120))[e];
    if (tid < 2) outbS[tid] = out_b[tid];

    const float outWl0 = out_W[cc0];
    const float outWl1 = out_W[128 + cc0];

    bf16x8 wl[4][8];                      // persistent layer1 weights (128 VGPRs)
    float b0c[4], bvc[4], b1c[4], M0c[4], M1c[4];
    float c0r[4] = {0.f, 0.f, 0.f, 0.f};
    float c1r[4] = {0.f, 0.f, 0.f, 0.f};

    auto load_consts = [&](const float* bb, const float* M, const float* V,
                           const unsigned short* W1) {
#pragma unroll
        for (int g = 0; g < 4; ++g) {
            const int n = g * 128 + cc0;
#pragma unroll
            for (int q = 0; q < 8; ++q)
                wl[g][q] = ld8(W1 + (size_t)n * 256 + quad * 8 + q * 32);
            b0c[g] = bb[n];
            b1c[g] = bb[512 + n];
            M0c[g] = M[n * 2 + 0];
            M1c[g] = M[n * 2 + 1];
            bvc[g] = bb[n] + V[n];
        }
    };
    auto load_w0 = [&](const unsigned short* W0) {
        for (int e = tid; e < 512 * 16; e += NT) {
            int n = e >> 4, j = e & 15;
            ushort8 v = *(const ushort8*)(W0 + n * 128 + j * 8);
            *(ushort8*)(&W0s[n * 128 + ((j ^ (n & 7)) << 3)]) = v;
        }
    };

    load_w0(W0e);
    load_consts(benc, Me, ve, W1e);
    __syncthreads();

    int cur = 0;

    // ================= encoder: 60 steps, 2 barriers/step =================
#pragma unroll 1
    for (int t = 0; t < 60; ++t) {
        // ---- layer 0 ----
        float p0[4], p1[4];
#pragma unroll
        for (int i = 0; i < 4; ++i) {
            float2 pv = *(const float2*)&histL[(quad * 4 + i) * 120 + 2 * t];
            p0[i] = pv.x; p1[i] = pv.y;
        }
        f32x4 acc[4];
#pragma unroll
        for (int g = 0; g < 4; ++g)
#pragma unroll
            for (int i = 0; i < 4; ++i)
                acc[g][i] = bvc[g] + M0c[g] * p0[i] + M1c[g] * p1[i];
        bf16x8 a0[4];
#pragma unroll
        for (int c = 0; c < 4; ++c)
            a0[c] = ld8(&A1[cur ^ 1][a1i(ln, quad * 8 + c * 32)]);
#pragma unroll
        for (int c = 0; c < 4; ++c)
#pragma unroll
            for (int g = 0; g < 4; ++g) {
                bf16x8 wb = ld8(&W0s[w0i(g * 128 + cc0, quad * 8 + c * 32)]);
                acc[g] = __builtin_amdgcn_mfma_f32_16x16x32_bf16(a0[c], wb, acc[g], 0, 0, 0);
            }
#pragma unroll
        for (int i = 0; i < 4; ++i) {
            float iv = sigm(acc[0][i]);
            float fv = sigm(acc[1][i]);
            float gv = tanh_(acc[2][i]);
            float ov = sigm(acc[3][i]);
            c0r[i] = fv * c0r[i] + iv * gv;
            float h = ov * tanh_(c0r[i]);
            A1[cur][a1i(quad * 4 + i, cc0)] = f2bf(h);
        }
        __syncthreads();
        // ---- layer 1 (register weights) ----
        f32x4 acc1[4];
#pragma unroll
        for (int g = 0; g < 4; ++g)
#pragma unroll
            for (int i = 0; i < 4; ++i) acc1[g][i] = b1c[g];
#pragma unroll
        for (int q = 0; q < 8; ++q) {
            bf16x8 af = ld8(&A1[cur][a1i(ln, quad * 8 + q * 32)]);
#pragma unroll
            for (int g = 0; g < 4; ++g)
                acc1[g] = __builtin_amdgcn_mfma_f32_16x16x32_bf16(af, wl[g][q], acc1[g], 0, 0, 0);
        }
#pragma unroll
        for (int i = 0; i < 4; ++i) {
            float iv = sigm(acc1[0][i]);
            float fv = sigm(acc1[1][i]);
            float gv = tanh_(acc1[2][i]);
            float ov = sigm(acc1[3][i]);
            c1r[i] = fv * c1r[i] + iv * gv;
            float h = ov * tanh_(c1r[i]);
            A1[cur ^ 1][a1i(quad * 4 + i, 128 + cc0)] = f2bf(h);
        }
        __syncthreads();
        cur ^= 1;
    }

    // swap to decoder weights (one-time)
    load_w0(W0d);
    load_consts(bdec, Md, vd, W1d);
    __syncthreads();

    // ================= decoder: 360 steps, 2 barriers/step =================
#pragma unroll 1
    for (int d = 0; d < 360; ++d) {
        // ---- layer 0 ----
        f32x4 acc[4];
        if (d == 0) {
#pragma unroll
            for (int g = 0; g < 4; ++g)
#pragma unroll
                for (int i = 0; i < 4; ++i) acc[g][i] = b0c[g];   // x = 0
        } else {
            float p0[4], p1[4];
#pragma unroll
            for (int i = 0; i < 4; ++i) {
                float2 pv = *(const float2*)&predb[cur][quad * 4 + i][0];
                p0[i] = pv.x; p1[i] = pv.y;
            }
#pragma unroll
            for (int g = 0; g < 4; ++g)
#pragma unroll
                for (int i = 0; i < 4; ++i)
                    acc[g][i] = bvc[g] + M0c[g] * p0[i] + M1c[g] * p1[i];
        }
        if (tid < 32) {   // store prev pred; init next pred accumulator with out_b
            int r = tid >> 1, dd = tid & 1;
            if (d > 0)
                out[(size_t)(row0 + r) * 720 + (size_t)(d - 1) * 2 + dd] = predb[cur][r][dd];
            predb[cur ^ 1][r][dd] = outbS[dd];
        }
        bf16x8 a0[4];
#pragma unroll
        for (int c = 0; c < 4; ++c)
            a0[c] = ld8(&A1[cur ^ 1][a1i(ln, quad * 8 + c * 32)]);
#pragma unroll
        for (int c = 0; c < 4; ++c)
#pragma unroll
            for (int g = 0; g < 4; ++g) {
                bf16x8 wb = ld8(&W0s[w0i(g * 128 + cc0, quad * 8 + c * 32)]);
                acc[g] = __builtin_amdgcn_mfma_f32_16x16x32_bf16(a0[c], wb, acc[g], 0, 0, 0);
            }
#pragma unroll
        for (int i = 0; i < 4; ++i) {
            float iv = sigm(acc[0][i]);
            float fv = sigm(acc[1][i]);
            float gv = tanh_(acc[2][i]);
            float ov = sigm(acc[3][i]);
            c0r[i] = fv * c0r[i] + iv * gv;
            float h = ov * tanh_(c0r[i]);
            A1[cur][a1i(quad * 4 + i, cc0)] = f2bf(h);
        }
        __syncthreads();
        // ---- layer 1 + projection ----
        f32x4 acc1[4];
#pragma unroll
        for (int g = 0; g < 4; ++g)
#pragma unroll
            for (int i = 0; i < 4; ++i) acc1[g][i] = b1c[g];
#pragma unroll
        for (int q = 0; q < 8; ++q) {
            bf16x8 af = ld8(&A1[cur][a1i(ln, quad * 8 + q * 32)]);
#pragma unroll
            for (int g = 0; g < 4; ++g)
                acc1[g] = __builtin_amdgcn_mfma_f32_16x16x32_bf16(af, wl[g][q], acc1[g], 0, 0, 0);
        }
        float pp[8];
#pragma unroll
        for (int i = 0; i < 4; ++i) {
            float iv = sigm(acc1[0][i]);
            float fv = sigm(acc1[1][i]);
            float gv = tanh_(acc1[2][i]);
            float ov = sigm(acc1[3][i]);
            c1r[i] = fv * c1r[i] + iv * gv;
            float h = ov * tanh_(c1r[i]);
            A1[cur ^ 1][a1i(quad * 4 + i, 128 + cc0)] = f2bf(h);
            pp[2 * i + 0] = h * outWl0;
            pp[2 * i + 1] = h * outWl1;
        }
#pragma unroll
        for (int m = 1; m <= 8; m <<= 1)
#pragma unroll
            for (int k = 0; k < 8; ++k) pp[k] += __shfl_xor(pp[k], m, 64);
        if (ln == 0) {
#pragma unroll
            for (int i = 0; i < 4; ++i) {
                atomicAdd(&predb[cur ^ 1][quad * 4 + i][0], pp[2 * i + 0]);
                atomicAdd(&predb[cur ^ 1][quad * 4 + i][1], pp[2 * i + 1]);
            }
        }
        __syncthreads();
        cur ^= 1;
    }
    // flush final prediction
    if (tid < 32) {
        int r = tid >> 1, dd = tid & 1;
        out[(size_t)(row0 + r) * 720 + 359 * 2 + dd] = predb[cur][r][dd];
    }
}

extern "C" void kernel_launch(void* const* d_in, const int* in_sizes, int n_in,
                              void* d_out, int out_size, void* d_ws, size_t ws_size,
                              hipStream_t stream) {
    const float* hist    = (const float*)d_in[0];
    const float* emb_W   = (const float*)d_in[1];
    const float* emb_b   = (const float*)d_in[2];
    const float* enc_Wih = (const float*)d_in[3];
    const float* enc_Whh = (const float*)d_in[4];
    const float* enc_bih = (const float*)d_in[5];
    const float* enc_bhh = (const float*)d_in[6];
    const float* dec_Wih = (const float*)d_in[7];
    const float* dec_Whh = (const float*)d_in[8];
    const float* dec_bih = (const float*)d_in[9];
    const float* dec_bhh = (const float*)d_in[10];
    const float* out_W   = (const float*)d_in[11];
    const float* out_b   = (const float*)d_in[12];

    char* ws = (char*)d_ws;
    unsigned short* W0e = (unsigned short*)(ws + 0);        // 512*128*2 = 131072
    unsigned short* W1e = (unsigned short*)(ws + 131072);   // 512*256*2 = 262144
    unsigned short* W0d = (unsigned short*)(ws + 393216);   // 131072
    unsigned short* W1d = (unsigned short*)(ws + 524288);   // 262144
    float* benc = (float*)(ws + 786432);
    float* bdec = (float*)(ws + 790528);
    float* Me   = (float*)(ws + 794624);
    float* Md   = (float*)(ws + 798720);
    float* ve   = (float*)(ws + 802816);
    float* vd   = (float*)(ws + 804864);

    prep_kernel<<<1024, 256, 0, stream>>>(emb_W, emb_b,
                                          enc_Wih, enc_Whh, dec_Wih, dec_Whh,
                                          enc_bih, enc_bhh, dec_bih, dec_bhh,
                                          W0e, W1e, W0d, W1d,
                                          benc, bdec, Me, Md, ve, vd);
    lstm_kernel<<<256, NT, 0, stream>>>(hist, W0e, W1e, W0d, W1d,
                                        benc, bdec, Me, Md, ve, vd,
                                        out_W, out_b, (float*)d_out);
}

// Round 5
// 1213.978 us; speedup vs baseline: 4.3391x; 1.7508x over previous
//
#include <hip/hip_runtime.h>
#include <stdint.h>

#define NT 512

typedef __attribute__((ext_vector_type(8))) __bf16 bf16x8;
typedef __attribute__((ext_vector_type(8))) unsigned short ushort8;
typedef __attribute__((ext_vector_type(4))) float f32x4;

static __device__ __forceinline__ unsigned short f2bf(float f) {
    union { float f; uint32_t u; } v; v.f = f;
    uint32_t r = v.u + 0x7fffu + ((v.u >> 16) & 1u);   // RNE
    return (unsigned short)(r >> 16);
}
// fast activations: v_exp + v_rcp (no IEEE divide)
static __device__ __forceinline__ float sigm(float x) {
    return __builtin_amdgcn_rcpf(1.0f + __expf(-x));
}
static __device__ __forceinline__ float tanh_(float x) {
    return 2.0f * __builtin_amdgcn_rcpf(1.0f + __expf(-2.0f * x)) - 1.0f;
}
static __device__ __forceinline__ bf16x8 ld8(const unsigned short* p) {
    return __builtin_bit_cast(bf16x8, *(const ushort8*)p);
}
static __device__ __forceinline__ float swz(float v, int imm) {
    // imm encodes BitMode: (xor<<10)|(or<<5)|and
    int r;
    if (imm == 0x0010) r = __builtin_amdgcn_ds_swizzle(__builtin_bit_cast(int, v), 0x0010);
    else               r = __builtin_amdgcn_ds_swizzle(__builtin_bit_cast(int, v), 0x0410);
    return __builtin_bit_cast(float, r);
}

// ---- prep: pack weights bf16 (W1 row-major fused, W0 in lane-read-order),
//      fold embedding into M (512x2) and v (512), sum biases ----
__global__ void prep_kernel(
    const float* __restrict__ emb_W, const float* __restrict__ emb_b,
    const float* __restrict__ enc_Wih, const float* __restrict__ enc_Whh,
    const float* __restrict__ dec_Wih, const float* __restrict__ dec_Whh,
    const float* __restrict__ enc_bih, const float* __restrict__ enc_bhh,
    const float* __restrict__ dec_bih, const float* __restrict__ dec_bhh,
    unsigned short* __restrict__ W0p, unsigned short* __restrict__ W1p,
    float* __restrict__ benc, float* __restrict__ bdec,
    float* __restrict__ Me, float* __restrict__ Md,
    float* __restrict__ ve, float* __restrict__ vd)
{
    int idx = blockIdx.x * blockDim.x + threadIdx.x;
    // W1 fused [Wih | Whh] layer1: 2 nets x 512 x 256 row-major
    if (idx < 2 * 512 * 256) {
        int net = idx >> 17;
        int rem = idx & 131071;
        int n = rem >> 8, k = rem & 255;
        const float* Wih = net ? dec_Wih : enc_Wih;
        const float* Whh = net ? dec_Whh : enc_Whh;
        float v = (k < 128) ? Wih[(size_t)(512 + n) * 128 + k]
                            : Whh[(size_t)(512 + n) * 128 + k - 128];
        W1p[(size_t)net * 131072 + rem] = f2bf(v);
    }
    // W0 (layer0 Whh) in lane-read-order: [net][c][g][w][ln][quad][8]
    if (idx < 2 * 512 * 128) {
        int net = idx >> 16;
        int rem = idx & 65535;
        int j = rem & 7, quad = (rem >> 3) & 3, ln = (rem >> 5) & 15;
        int w = (rem >> 9) & 7, g = (rem >> 12) & 3, c = (rem >> 14) & 3;
        int n = g * 128 + w * 16 + ln;
        int k = c * 32 + quad * 8 + j;
        const float* Whh = net ? dec_Whh : enc_Whh;
        W0p[(size_t)net * 65536 + rem] = f2bf(Whh[(size_t)n * 128 + k]);
    }
    if (idx < 2048) {
        int net = idx >> 10;
        int rem = idx & 1023;
        float v = net ? (dec_bih[rem] + dec_bhh[rem]) : (enc_bih[rem] + enc_bhh[rem]);
        (net ? bdec : benc)[rem] = v;
    }
    if (idx < 1024) {
        int net = idx >> 9, n = idx & 511;
        const float* Wih = net ? dec_Wih : enc_Wih;
        float m0 = 0.f, m1 = 0.f, vv = 0.f;
        for (int k = 0; k < 128; ++k) {
            float wv = Wih[(size_t)n * 128 + k];
            m0 += wv * emb_W[k * 2 + 0];
            m1 += wv * emb_W[k * 2 + 1];
            vv += wv * emb_b[k];
        }
        float* M = net ? Md : Me;
        float* V = net ? vd : ve;
        M[n * 2 + 0] = m0; M[n * 2 + 1] = m1; V[n] = vv;
    }
}

__global__ __launch_bounds__(NT, 2) void lstm_kernel(
    const float* __restrict__ hist,
    const unsigned short* __restrict__ W0p, const unsigned short* __restrict__ W1p,
    const float* __restrict__ benc, const float* __restrict__ bdec,
    const float* __restrict__ Me, const float* __restrict__ Md,
    const float* __restrict__ ve, const float* __restrict__ vd,
    const float* __restrict__ out_W, const float* __restrict__ out_b,
    float* __restrict__ out)
{
    // A1: 2 buffers x [colchunk C(8)][row(16)][gq(4)][8] ushorts; gq = ((col>>3)&3) ^ ((row>>2)&3)
    __shared__ __align__(16) unsigned short A1s[2 * 4096];
    __shared__ __align__(16) unsigned short W0Ls[65536];   // [c][g][w][ln][quad][8]
    __shared__ __align__(16) float histL[16 * 120];

    const int tid = threadIdx.x;
    const int lane = tid & 63;
    const int w = tid >> 6;
    const int ln = lane & 15;
    const int quad = lane >> 4;
    const int row0 = blockIdx.x * 16;
    const int cc0 = w * 16 + ln;
    const int cg = (cc0 >> 3) & 3;

    // lane-constant LDS pointers (element = ushort units)
    const unsigned short* a1r = A1s + ln * 32 + ((quad ^ ((ln >> 2) & 3)) * 8);
    unsigned short* a1w = A1s + (cc0 >> 5) * 512 + quad * 128 + ((cg ^ quad) * 8) + (ln & 7);
    const unsigned short* w0b[4];
#pragma unroll
    for (int c = 0; c < 4; ++c)
        w0b[c] = W0Ls + c * 16384 + w * 512 + ln * 32 + quad * 8;

    for (int e = tid; e < 1024; e += NT) ((uint4*)A1s)[e] = make_uint4(0u, 0u, 0u, 0u);
    for (int e = tid; e < 480; e += NT)
        ((float4*)histL)[e] = ((const float4*)(hist + (size_t)row0 * 120))[e];

    // output projection constants (bf16 B-fragment of out_W, col n = ln; clamp n>=2 to 0)
    const int nidx = (ln < 2) ? ln : 0;
    const float outbL = out_b[nidx];
    bf16x8 ow[4];
#pragma unroll
    for (int c = 0; c < 4; ++c) {
        unsigned short tmp[8];
#pragma unroll
        for (int j = 0; j < 8; ++j)
            tmp[j] = f2bf(out_W[nidx * 128 + c * 32 + quad * 8 + j]);
        ow[c] = __builtin_bit_cast(bf16x8, *(ushort8*)tmp);
    }

    bf16x8 wl[4][8];                      // persistent layer1 weights
    float b0c[4], bvc[4], b1c[4], M0c[4], M1c[4];
    float c0r[4] = {0.f, 0.f, 0.f, 0.f};
    float c1r[4] = {0.f, 0.f, 0.f, 0.f};

    auto load_consts = [&](const float* bb, const float* M, const float* V,
                           const unsigned short* W1) {
#pragma unroll
        for (int g = 0; g < 4; ++g) {
            const int n = g * 128 + cc0;
#pragma unroll
            for (int q = 0; q < 8; ++q)
                wl[g][q] = ld8(W1 + (size_t)n * 256 + quad * 8 + q * 32);
            b0c[g] = bb[n];
            b1c[g] = bb[512 + n];
            M0c[g] = M[n * 2 + 0];
            M1c[g] = M[n * 2 + 1];
            bvc[g] = bb[n] + V[n];
        }
    };
    auto copy_w0 = [&](const unsigned short* src) {   // 128 KB linear copy
        for (int e = tid; e < 8192; e += NT)
            ((uint4*)W0Ls)[e] = ((const uint4*)src)[e];
    };

    copy_w0(W0p);
    load_consts(benc, Me, ve, W1p);
    __syncthreads();

    // ---------------- encoder step (buf = t&1, literal) ----------------
    auto enc_step = [&](int t, int buf) {
        bf16x8 a0[4];
#pragma unroll
        for (int c = 0; c < 4; ++c)
            a0[c] = ld8(a1r + (buf ^ 1) * 4096 + c * 512);
        f32x4 acc[4];
#pragma unroll
        for (int g = 0; g < 4; ++g)
#pragma unroll
            for (int i = 0; i < 4; ++i) {
                float2 pv = *(const float2*)&histL[(quad * 4 + i) * 120 + 2 * t];
                acc[g][i] = bvc[g] + M0c[g] * pv.x + M1c[g] * pv.y;
            }
#pragma unroll
        for (int c = 0; c < 4; ++c)
#pragma unroll
            for (int g = 0; g < 4; ++g)
                acc[g] = __builtin_amdgcn_mfma_f32_16x16x32_bf16(a0[c], ld8(w0b[c] + g * 4096), acc[g], 0, 0, 0);
#pragma unroll
        for (int i = 0; i < 4; ++i) {
            float iv = sigm(acc[0][i]);
            float fv = sigm(acc[1][i]);
            float gv = tanh_(acc[2][i]);
            float ov = sigm(acc[3][i]);
            c0r[i] = fv * c0r[i] + iv * gv;
            a1w[buf * 4096 + i * 32] = f2bf(ov * tanh_(c0r[i]));
        }
        __syncthreads();
        f32x4 acc1[4];
#pragma unroll
        for (int g = 0; g < 4; ++g)
#pragma unroll
            for (int i = 0; i < 4; ++i) acc1[g][i] = b1c[g];
#pragma unroll
        for (int q = 0; q < 8; ++q) {
            bf16x8 af = ld8(a1r + buf * 4096 + q * 512);
#pragma unroll
            for (int g = 0; g < 4; ++g)
                acc1[g] = __builtin_amdgcn_mfma_f32_16x16x32_bf16(af, wl[g][q], acc1[g], 0, 0, 0);
        }
#pragma unroll
        for (int i = 0; i < 4; ++i) {
            float iv = sigm(acc1[0][i]);
            float fv = sigm(acc1[1][i]);
            float gv = tanh_(acc1[2][i]);
            float ov = sigm(acc1[3][i]);
            c1r[i] = fv * c1r[i] + iv * gv;
            a1w[(buf ^ 1) * 4096 + 2048 + i * 32] = f2bf(ov * tanh_(c1r[i]));
        }
        __syncthreads();
    };

    for (int t = 0; t < 60; t += 2) { enc_step(t, 0); enc_step(t + 1, 1); }

    // swap to decoder weights
    copy_w0(W0p + 65536);
    load_consts(bdec, Md, vd, W1p + 131072);
    __syncthreads();

    // ---------------- decoder step (buf = d&1, literal) ----------------
    auto dec_step = [&](int d, int buf) {
        f32x4 acc[4];
        if (d > 0) {
            // projection of h1(d-1): 4 MFMAs, bias, store, broadcast
            f32x4 pacc = {0.f, 0.f, 0.f, 0.f};
#pragma unroll
            for (int c = 0; c < 4; ++c) {
                bf16x8 ah = ld8(a1r + buf * 4096 + (4 + c) * 512);
                pacc = __builtin_amdgcn_mfma_f32_16x16x32_bf16(ah, ow[c], pacc, 0, 0, 0);
            }
            float pd[4];
#pragma unroll
            for (int i = 0; i < 4; ++i) pd[i] = pacc[i] + outbL;
            if (w == 0 && ln < 2) {
#pragma unroll
                for (int i = 0; i < 4; ++i)
                    out[(size_t)(row0 + quad * 4 + i) * 720 + (size_t)(d - 1) * 2 + ln] = pd[i];
            }
#pragma unroll
            for (int g = 0; g < 4; ++g)
#pragma unroll
                for (int i = 0; i < 4; ++i) acc[g][i] = bvc[g];
#pragma unroll
            for (int i = 0; i < 4; ++i) {
                float p0 = swz(pd[i], 0x0010);
                float p1 = swz(pd[i], 0x0410);
#pragma unroll
                for (int g = 0; g < 4; ++g)
                    acc[g][i] += M0c[g] * p0 + M1c[g] * p1;
            }
        } else {
#pragma unroll
            for (int g = 0; g < 4; ++g)
#pragma unroll
                for (int i = 0; i < 4; ++i) acc[g][i] = b0c[g];
        }
        bf16x8 a0[4];
#pragma unroll
        for (int c = 0; c < 4; ++c)
            a0[c] = ld8(a1r + (buf ^ 1) * 4096 + c * 512);
#pragma unroll
        for (int c = 0; c < 4; ++c)
#pragma unroll
            for (int g = 0; g < 4; ++g)
                acc[g] = __builtin_amdgcn_mfma_f32_16x16x32_bf16(a0[c], ld8(w0b[c] + g * 4096), acc[g], 0, 0, 0);
#pragma unroll
        for (int i = 0; i < 4; ++i) {
            float iv = sigm(acc[0][i]);
            float fv = sigm(acc[1][i]);
            float gv = tanh_(acc[2][i]);
            float ov = sigm(acc[3][i]);
            c0r[i] = fv * c0r[i] + iv * gv;
            a1w[buf * 4096 + i * 32] = f2bf(ov * tanh_(c0r[i]));
        }
        __syncthreads();
        f32x4 acc1[4];
#pragma unroll
        for (int g = 0; g < 4; ++g)
#pragma unroll
            for (int i = 0; i < 4; ++i) acc1[g][i] = b1c[g];
#pragma unroll
        for (int q = 0; q < 8; ++q) {
            bf16x8 af = ld8(a1r + buf * 4096 + q * 512);
#pragma unroll
            for (int g = 0; g < 4; ++g)
                acc1[g] = __builtin_amdgcn_mfma_f32_16x16x32_bf16(af, wl[g][q], acc1[g], 0, 0, 0);
        }
#pragma unroll
        for (int i = 0; i < 4; ++i) {
            float iv = sigm(acc1[0][i]);
            float fv = sigm(acc1[1][i]);
            float gv = tanh_(acc1[2][i]);
            float ov = sigm(acc1[3][i]);
            c1r[i] = fv * c1r[i] + iv * gv;
            a1w[(buf ^ 1) * 4096 + 2048 + i * 32] = f2bf(ov * tanh_(c1r[i]));
        }
        __syncthreads();
    };

    for (int d = 0; d < 360; d += 2) { dec_step(d, 0); dec_step(d + 1, 1); }

    // final projection (h1(359) lives in buffer 0)
    {
        f32x4 pacc = {0.f, 0.f, 0.f, 0.f};
#pragma unroll
        for (int c = 0; c < 4; ++c) {
            bf16x8 ah = ld8(a1r + 0 * 4096 + (4 + c) * 512);
            pacc = __builtin_amdgcn_mfma_f32_16x16x32_bf16(ah, ow[c], pacc, 0, 0, 0);
        }
        if (w == 0 && ln < 2) {
#pragma unroll
            for (int i = 0; i < 4; ++i)
                out[(size_t)(row0 + quad * 4 + i) * 720 + 359 * 2 + ln] = pacc[i] + outbL;
        }
    }
}

extern "C" void kernel_launch(void* const* d_in, const int* in_sizes, int n_in,
                              void* d_out, int out_size, void* d_ws, size_t ws_size,
                              hipStream_t stream) {
    const float* hist    = (const float*)d_in[0];
    const float* emb_W   = (const float*)d_in[1];
    const float* emb_b   = (const float*)d_in[2];
    const float* enc_Wih = (const float*)d_in[3];
    const float* enc_Whh = (const float*)d_in[4];
    const float* enc_bih = (const float*)d_in[5];
    const float* enc_bhh = (const float*)d_in[6];
    const float* dec_Wih = (const float*)d_in[7];
    const float* dec_Whh = (const float*)d_in[8];
    const float* dec_bih = (const float*)d_in[9];
    const float* dec_bhh = (const float*)d_in[10];
    const float* out_W   = (const float*)d_in[11];
    const float* out_b   = (const float*)d_in[12];

    char* ws = (char*)d_ws;
    unsigned short* W0p = (unsigned short*)(ws + 0);        // 2*512*128*2 = 262144 B
    unsigned short* W1p = (unsigned short*)(ws + 262144);   // 2*512*256*2 = 524288 B
    float* benc = (float*)(ws + 786432);
    float* bdec = (float*)(ws + 790528);
    float* Me   = (float*)(ws + 794624);
    float* Md   = (float*)(ws + 798720);
    float* ve   = (float*)(ws + 802816);
    float* vd   = (float*)(ws + 804864);

    prep_kernel<<<1024, 256, 0, stream>>>(emb_W, emb_b,
                                          enc_Wih, enc_Whh, dec_Wih, dec_Whh,
                                          enc_bih, enc_bhh, dec_bih, dec_bhh,
                                          W0p, W1p, benc, bdec, Me, Md, ve, vd);
    lstm_kernel<<<256, NT, 0, stream>>>(hist, W0p, W1p,
                                        benc, bdec, Me, Md, ve, vd,
                                        out_W, out_b, (float*)d_out);
}

// Round 7
// 1024.618 us; speedup vs baseline: 5.1410x; 1.1848x over previous
//
#include <hip/hip_runtime.h>
#include <stdint.h>

#define NT 512

typedef __attribute__((ext_vector_type(8))) __bf16 bf16x8;
typedef __attribute__((ext_vector_type(8))) unsigned short ushort8;
typedef __attribute__((ext_vector_type(4))) float f32x4;

static __device__ __forceinline__ unsigned short f2bf(float f) {
    union { float f; uint32_t u; } v; v.f = f;
    uint32_t r = v.u + 0x7fffu + ((v.u >> 16) & 1u);   // RNE
    return (unsigned short)(r >> 16);
}
static __device__ __forceinline__ float sigm(float x) {
    return __builtin_amdgcn_rcpf(1.0f + __expf(-x));
}
static __device__ __forceinline__ float tanh_(float x) {
    return 2.0f * __builtin_amdgcn_rcpf(1.0f + __expf(-2.0f * x)) - 1.0f;
}
static __device__ __forceinline__ bf16x8 ld8(const unsigned short* p) {
    return __builtin_bit_cast(bf16x8, *(const ushort8*)p);
}
static __device__ __forceinline__ float swz(float v, int imm) {
    int r;
    if (imm == 0x0010) r = __builtin_amdgcn_ds_swizzle(__builtin_bit_cast(int, v), 0x0010);
    else               r = __builtin_amdgcn_ds_swizzle(__builtin_bit_cast(int, v), 0x0410);
    return __builtin_bit_cast(float, r);
}

// ---- prep: identical packing to round 5 ----
__global__ void prep_kernel(
    const float* __restrict__ emb_W, const float* __restrict__ emb_b,
    const float* __restrict__ enc_Wih, const float* __restrict__ enc_Whh,
    const float* __restrict__ dec_Wih, const float* __restrict__ dec_Whh,
    const float* __restrict__ enc_bih, const float* __restrict__ enc_bhh,
    const float* __restrict__ dec_bih, const float* __restrict__ dec_bhh,
    unsigned short* __restrict__ W0p, unsigned short* __restrict__ W1p,
    float* __restrict__ benc, float* __restrict__ bdec,
    float* __restrict__ Me, float* __restrict__ Md,
    float* __restrict__ ve, float* __restrict__ vd)
{
    int idx = blockIdx.x * blockDim.x + threadIdx.x;
    if (idx < 2 * 512 * 256) {
        int net = idx >> 17;
        int rem = idx & 131071;
        int n = rem >> 8, k = rem & 255;
        const float* Wih = net ? dec_Wih : enc_Wih;
        const float* Whh = net ? dec_Whh : enc_Whh;
        float v = (k < 128) ? Wih[(size_t)(512 + n) * 128 + k]
                            : Whh[(size_t)(512 + n) * 128 + k - 128];
        W1p[(size_t)net * 131072 + rem] = f2bf(v);
    }
    // W0 (layer0 Whh) lane-read-order: [net][c][g][w][ln][quad][8]
    if (idx < 2 * 512 * 128) {
        int net = idx >> 16;
        int rem = idx & 65535;
        int j = rem & 7, quad = (rem >> 3) & 3, ln = (rem >> 5) & 15;
        int w = (rem >> 9) & 7, g = (rem >> 12) & 3, c = (rem >> 14) & 3;
        int n = g * 128 + w * 16 + ln;
        int k = c * 32 + quad * 8 + j;
        const float* Whh = net ? dec_Whh : enc_Whh;
        W0p[(size_t)net * 65536 + rem] = f2bf(Whh[(size_t)n * 128 + k]);
    }
    if (idx < 2048) {
        int net = idx >> 10;
        int rem = idx & 1023;
        float v = net ? (dec_bih[rem] + dec_bhh[rem]) : (enc_bih[rem] + enc_bhh[rem]);
        (net ? bdec : benc)[rem] = v;
    }
    if (idx < 1024) {
        int net = idx >> 9, n = idx & 511;
        const float* Wih = net ? dec_Wih : enc_Wih;
        float m0 = 0.f, m1 = 0.f, vv = 0.f;
        for (int k = 0; k < 128; ++k) {
            float wv = Wih[(size_t)n * 128 + k];
            m0 += wv * emb_W[k * 2 + 0];
            m1 += wv * emb_W[k * 2 + 1];
            vv += wv * emb_b[k];
        }
        float* M = net ? Md : Me;
        float* V = net ? vd : ve;
        M[n * 2 + 0] = m0; M[n * 2 + 1] = m1; V[n] = vv;
    }
}

__global__ __launch_bounds__(NT, 2) void lstm_kernel(
    const float* __restrict__ hist,
    const unsigned short* __restrict__ W0p, const unsigned short* __restrict__ W1p,
    const float* __restrict__ benc, const float* __restrict__ bdec,
    const float* __restrict__ Me, const float* __restrict__ Md,
    const float* __restrict__ ve, const float* __restrict__ vd,
    const float* __restrict__ out_W, const float* __restrict__ out_b,
    float* __restrict__ out)
{
    // A1: 2 buffers x [chunk(8)][row(16)][gq(4)][8]; gq = ((col>>3)&3) ^ (row>>2)
    __shared__ __align__(16) unsigned short A1s[2 * 4096];
    // W0: [c][g][w][ln][quad ^ ((ln>>1)&3)][8]  (granule-swizzled -> 2-way max)
    __shared__ __align__(16) unsigned short W0Ls[65536];
    __shared__ __align__(16) float histL[16 * 120];

    const int tid = threadIdx.x;
    const int lane = tid & 63;
    const int w = tid >> 6;
    const int ln = lane & 15;
    const int quad = lane >> 4;
    const int row0 = blockIdx.x * 16;
    const int cc0 = w * 16 + ln;
    const int cg = (cc0 >> 3) & 3;

    const unsigned short* a1r = A1s + ln * 32 + ((quad ^ ((ln >> 2) & 3)) * 8);
    unsigned short* a1w = A1s + (cc0 >> 5) * 512 + quad * 128 + ((cg ^ quad) * 8) + (ln & 7);
    const unsigned short* w0b[4];
#pragma unroll
    for (int c = 0; c < 4; ++c)
        w0b[c] = W0Ls + c * 16384 + w * 512 + ln * 32 + ((quad ^ ((ln >> 1) & 3)) * 8);

    // zero h1(-1): buf0 chunks 4..7 = ushorts 2048..4095 = uint4 256..511
    for (int e = tid; e < 256; e += NT) ((uint4*)A1s)[256 + e] = make_uint4(0u, 0u, 0u, 0u);
    for (int e = tid; e < 480; e += NT)
        ((float4*)histL)[e] = ((const float4*)(hist + (size_t)row0 * 120))[e];

    // projection B-fragment (col n = ln<2, else dup col0 - unused lanes)
    const int nidx = (ln < 2) ? ln : 0;
    const float outbL = out_b[nidx];
    bf16x8 ow[4];
#pragma unroll
    for (int c = 0; c < 4; ++c) {
        unsigned short tmp[8];
#pragma unroll
        for (int j = 0; j < 8; ++j)
            tmp[j] = f2bf(out_W[nidx * 128 + c * 32 + quad * 8 + j]);
        ow[c] = __builtin_bit_cast(bf16x8, *(ushort8*)tmp);
    }

    bf16x8 wl[4][8];                      // persistent layer1 weights
    float b0c[4], bvc[4], b1c[4], M0c[4], M1c[4];
    float c0r[4] = {0.f, 0.f, 0.f, 0.f};
    float c1r[4] = {0.f, 0.f, 0.f, 0.f};

    auto load_consts = [&](const float* bb, const float* M, const float* V,
                           const unsigned short* W1) {
#pragma unroll
        for (int g = 0; g < 4; ++g) {
            const int n = g * 128 + cc0;
#pragma unroll
            for (int q = 0; q < 8; ++q)
                wl[g][q] = ld8(W1 + (size_t)n * 256 + quad * 8 + q * 32);
            b0c[g] = bb[n];
            b1c[g] = bb[512 + n];
            M0c[g] = M[n * 2 + 0];
            M1c[g] = M[n * 2 + 1];
            bvc[g] = bb[n] + V[n];
        }
    };
    auto copy_w0 = [&](const unsigned short* src) {   // swizzled 128 KB copy
        for (int e = tid; e < 8192; e += NT) {
            int d = (e & ~3) | ((e & 3) ^ ((e >> 3) & 3));
            ((uint4*)W0Ls)[d] = ((const uint4*)src)[e];
        }
    };

    copy_w0(W0p);
    load_consts(benc, Me, ve, W1p);
    __syncthreads();

    // prologue: h0(0) = f(x(0), h=0, c=0) -> buf0 chunks 0..3
    {
        f32x4 z[4];
#pragma unroll
        for (int i = 0; i < 4; ++i) {
            float x0 = hist[(size_t)(row0 + quad * 4 + i) * 120 + 0];
            float x1 = hist[(size_t)(row0 + quad * 4 + i) * 120 + 1];
#pragma unroll
            for (int g = 0; g < 4; ++g) z[g][i] = bvc[g] + M0c[g] * x0 + M1c[g] * x1;
        }
#pragma unroll
        for (int i = 0; i < 4; ++i) {
            float iv = sigm(z[0][i]);
            float gv = tanh_(z[2][i]);
            float ov = sigm(z[3][i]);
            c0r[i] = iv * gv;
            a1w[i * 32] = f2bf(ov * tanh_(c0r[i]));
        }
    }
    __syncthreads();

    // ======= encoder superphase S_t: layer1(t) + layer0(t+1), 1 barrier =======
    auto enc_step = [&](int t, int buf) {
        bf16x8 af[8];
#pragma unroll
        for (int q = 0; q < 8; ++q)
            af[q] = ld8(a1r + buf * 4096 + q * 512);
        f32x4 acc1[4];
#pragma unroll
        for (int g = 0; g < 4; ++g)
#pragma unroll
            for (int i = 0; i < 4; ++i) acc1[g][i] = b1c[g];
#pragma unroll
        for (int q = 0; q < 8; ++q)
#pragma unroll
            for (int g = 0; g < 4; ++g)
                acc1[g] = __builtin_amdgcn_mfma_f32_16x16x32_bf16(af[q], wl[g][q], acc1[g], 0, 0, 0);
        f32x4 acc0[4];
#pragma unroll
        for (int g = 0; g < 4; ++g)
#pragma unroll
            for (int i = 0; i < 4; ++i) {
                float2 pv = *(const float2*)&histL[(quad * 4 + i) * 120 + 2 * (t + 1)];
                acc0[g][i] = bvc[g] + M0c[g] * pv.x + M1c[g] * pv.y;
            }
#pragma unroll
        for (int c = 0; c < 4; ++c)
#pragma unroll
            for (int g = 0; g < 4; ++g)
                acc0[g] = __builtin_amdgcn_mfma_f32_16x16x32_bf16(af[c], ld8(w0b[c] + g * 4096), acc0[g], 0, 0, 0);
#pragma unroll
        for (int i = 0; i < 4; ++i) {       // layer1(t) elementwise
            float iv = sigm(acc1[0][i]);
            float fv = sigm(acc1[1][i]);
            float gv = tanh_(acc1[2][i]);
            float ov = sigm(acc1[3][i]);
            c1r[i] = fv * c1r[i] + iv * gv;
            a1w[(buf ^ 1) * 4096 + 2048 + i * 32] = f2bf(ov * tanh_(c1r[i]));
        }
#pragma unroll
        for (int i = 0; i < 4; ++i) {       // layer0(t+1) elementwise
            float iv = sigm(acc0[0][i]);
            float fv = sigm(acc0[1][i]);
            float gv = tanh_(acc0[2][i]);
            float ov = sigm(acc0[3][i]);
            c0r[i] = fv * c0r[i] + iv * gv;
            a1w[(buf ^ 1) * 4096 + i * 32] = f2bf(ov * tanh_(c0r[i]));
        }
        __syncthreads();
    };

    for (int t = 0; t < 58; t += 2) { enc_step(t, 0); enc_step(t + 1, 1); }
    enc_step(58, 0);                        // S_58 -> writes buf1 (h0(59), h1(58))

    // ======= S_59: layer1_enc(59); swap to decoder; layer0_dec(0) =======
    {
        bf16x8 af[8];
#pragma unroll
        for (int q = 0; q < 8; ++q)
            af[q] = ld8(a1r + 4096 + q * 512);            // buf1
        f32x4 acc1[4];
#pragma unroll
        for (int g = 0; g < 4; ++g)
#pragma unroll
            for (int i = 0; i < 4; ++i) acc1[g][i] = b1c[g];
#pragma unroll
        for (int q = 0; q < 8; ++q)
#pragma unroll
            for (int g = 0; g < 4; ++g)
                acc1[g] = __builtin_amdgcn_mfma_f32_16x16x32_bf16(af[q], wl[g][q], acc1[g], 0, 0, 0);
#pragma unroll
        for (int i = 0; i < 4; ++i) {
            float iv = sigm(acc1[0][i]);
            float fv = sigm(acc1[1][i]);
            float gv = tanh_(acc1[2][i]);
            float ov = sigm(acc1[3][i]);
            c1r[i] = fv * c1r[i] + iv * gv;
            a1w[2048 + i * 32] = f2bf(ov * tanh_(c1r[i]));    // h1(59) -> buf0[4..7]
        }
        copy_w0(W0p + 65536);               // decoder weights (no W0 reads this phase)
        load_consts(bdec, Md, vd, W1p + 131072);
        __syncthreads();
        // layer0_dec(0): x = 0, h = h0(59) = af[0..3]
        f32x4 acc0[4];
#pragma unroll
        for (int g = 0; g < 4; ++g) acc0[g] = (f32x4){0.f, 0.f, 0.f, 0.f};
#pragma unroll
        for (int c = 0; c < 4; ++c)
#pragma unroll
            for (int g = 0; g < 4; ++g)
                acc0[g] = __builtin_amdgcn_mfma_f32_16x16x32_bf16(af[c], ld8(w0b[c] + g * 4096), acc0[g], 0, 0, 0);
#pragma unroll
        for (int i = 0; i < 4; ++i) {
            float iv = sigm(acc0[0][i] + b0c[0]);
            float fv = sigm(acc0[1][i] + b0c[1]);
            float gv = tanh_(acc0[2][i] + b0c[2]);
            float ov = sigm(acc0[3][i] + b0c[3]);
            c0r[i] = fv * c0r[i] + iv * gv;
            a1w[i * 32] = f2bf(ov * tanh_(c0r[i]));           // h0_d(0) -> buf0[0..3]
        }
        __syncthreads();
    }

    // ======= decoder D_d: ph1 layer1(d)+W0·h0(d); ph2 proj(d)+finish layer0(d+1) =======
    auto dec_step = [&](int d, int buf) {
        bf16x8 af[8];
#pragma unroll
        for (int q = 0; q < 8; ++q)
            af[q] = ld8(a1r + buf * 4096 + q * 512);
        f32x4 acc1[4];
#pragma unroll
        for (int g = 0; g < 4; ++g)
#pragma unroll
            for (int i = 0; i < 4; ++i) acc1[g][i] = b1c[g];
#pragma unroll
        for (int q = 0; q < 8; ++q)
#pragma unroll
            for (int g = 0; g < 4; ++g)
                acc1[g] = __builtin_amdgcn_mfma_f32_16x16x32_bf16(af[q], wl[g][q], acc1[g], 0, 0, 0);
        f32x4 acc0[4];
#pragma unroll
        for (int g = 0; g < 4; ++g) acc0[g] = (f32x4){0.f, 0.f, 0.f, 0.f};
#pragma unroll
        for (int c = 0; c < 4; ++c)
#pragma unroll
            for (int g = 0; g < 4; ++g)
                acc0[g] = __builtin_amdgcn_mfma_f32_16x16x32_bf16(af[c], ld8(w0b[c] + g * 4096), acc0[g], 0, 0, 0);
#pragma unroll
        for (int i = 0; i < 4; ++i) {       // layer1(d) elementwise
            float iv = sigm(acc1[0][i]);
            float fv = sigm(acc1[1][i]);
            float gv = tanh_(acc1[2][i]);
            float ov = sigm(acc1[3][i]);
            c1r[i] = fv * c1r[i] + iv * gv;
            a1w[(buf ^ 1) * 4096 + 2048 + i * 32] = f2bf(ov * tanh_(c1r[i]));
        }
        __syncthreads();
        // phase 2: projection of h1(d) (2 parallel MFMA chains)
        f32x4 pa = {0.f, 0.f, 0.f, 0.f}, pb = {0.f, 0.f, 0.f, 0.f};
        pa = __builtin_amdgcn_mfma_f32_16x16x32_bf16(ld8(a1r + (buf ^ 1) * 4096 + 4 * 512), ow[0], pa, 0, 0, 0);
        pb = __builtin_amdgcn_mfma_f32_16x16x32_bf16(ld8(a1r + (buf ^ 1) * 4096 + 5 * 512), ow[1], pb, 0, 0, 0);
        pa = __builtin_amdgcn_mfma_f32_16x16x32_bf16(ld8(a1r + (buf ^ 1) * 4096 + 6 * 512), ow[2], pa, 0, 0, 0);
        pb = __builtin_amdgcn_mfma_f32_16x16x32_bf16(ld8(a1r + (buf ^ 1) * 4096 + 7 * 512), ow[3], pb, 0, 0, 0);
        float pd[4];
#pragma unroll
        for (int i = 0; i < 4; ++i) pd[i] = pa[i] + pb[i] + outbL;
        if (w == 0 && ln < 2) {
#pragma unroll
            for (int i = 0; i < 4; ++i)
                out[(size_t)(row0 + quad * 4 + i) * 720 + (size_t)d * 2 + ln] = pd[i];
        }
#pragma unroll
        for (int i = 0; i < 4; ++i) {       // finish layer0(d+1): x = embed(pred(d))
            float p0 = swz(pd[i], 0x0010);
            float p1 = swz(pd[i], 0x0410);
            float z0 = acc0[0][i] + bvc[0] + M0c[0] * p0 + M1c[0] * p1;
            float z1 = acc0[1][i] + bvc[1] + M0c[1] * p0 + M1c[1] * p1;
            float z2 = acc0[2][i] + bvc[2] + M0c[2] * p0 + M1c[2] * p1;
            float z3 = acc0[3][i] + bvc[3] + M0c[3] * p0 + M1c[3] * p1;
            float iv = sigm(z0);
            float fv = sigm(z1);
            float gv = tanh_(z2);
            float ov = sigm(z3);
            c0r[i] = fv * c0r[i] + iv * gv;
            a1w[(buf ^ 1) * 4096 + i * 32] = f2bf(ov * tanh_(c0r[i]));
        }
        __syncthreads();
    };

    for (int d = 0; d < 360; d += 2) { dec_step(d, 0); dec_step(d + 1, 1); }
}

extern "C" void kernel_launch(void* const* d_in, const int* in_sizes, int n_in,
                              void* d_out, int out_size, void* d_ws, size_t ws_size,
                              hipStream_t stream) {
    const float* hist    = (const float*)d_in[0];
    const float* emb_W   = (const float*)d_in[1];
    const float* emb_b   = (const float*)d_in[2];
    const float* enc_Wih = (const float*)d_in[3];
    const float* enc_Whh = (const float*)d_in[4];
    const float* enc_bih = (const float*)d_in[5];
    const float* enc_bhh = (const float*)d_in[6];
    const float* dec_Wih = (const float*)d_in[7];
    const float* dec_Whh = (const float*)d_in[8];
    const float* dec_bih = (const float*)d_in[9];
    const float* dec_bhh = (const float*)d_in[10];
    const float* out_W   = (const float*)d_in[11];
    const float* out_b   = (const float*)d_in[12];

    char* ws = (char*)d_ws;
    unsigned short* W0p = (unsigned short*)(ws + 0);        // 2*512*128*2 = 262144 B
    unsigned short* W1p = (unsigned short*)(ws + 262144);   // 2*512*256*2 = 524288 B
    float* benc = (float*)(ws + 786432);
    float* bdec = (float*)(ws + 790528);
    float* Me   = (float*)(ws + 794624);
    float* Md   = (float*)(ws + 798720);
    float* ve   = (float*)(ws + 802816);
    float* vd   = (float*)(ws + 804864);

    prep_kernel<<<1024, 256, 0, stream>>>(emb_W, emb_b,
                                          enc_Wih, enc_Whh, dec_Wih, dec_Whh,
                                          enc_bih, enc_bhh, dec_bih, dec_bhh,
                                          W0p, W1p, benc, bdec, Me, Md, ve, vd);
    lstm_kernel<<<256, NT, 0, stream>>>(hist, W0p, W1p,
                                        benc, bdec, Me, Md, ve, vd,
                                        out_W, out_b, (float*)d_out);
}